// Round 8
// baseline (424.355 us; speedup 1.0000x reference)
//
#include <hip/hip_runtime.h>

// Problem constants (from reference)
#define DCOLS 32        // dist/angle columns
#define WCOLS 32        // idx_t/index_t columns
#define NUM_CLASSES 22
#define ONEHOT_COLS (NUM_CLASSES * WCOLS)       // 704
#define OUT_COLS (ONEHOT_COLS + WCOLS + WCOLS)  // 768
#define ROWS_PER_BLOCK 8                        // 8 rows x 32 cols = 256 gather threads

// ---------------------------------------------------------------------------
// Min/max encoding (ws[0..1] seeded with 0xFF bytes by hipMemsetAsync):
//   ws[0] (uint): running MIN of bits(-v); v>=0 -> uint-min tracks float-min.
//   ws[1] (int):  running MAX of bits(v);  v>=0 -> int order == float order.
// Recover: dmin = -as_float(ws[0]);  dmax = as_float(ws[1]).
//
// R8 experiment: R4 structure exactly, but PLAIN cached stores instead of
// nontemporal (R3->R4 confounded NT with the 128->256 loader change; the
// harness's own fillBuffer sustains 6.4 TB/s with plain stores, and FETCH
// counters showed the "protect L2" rationale for NT was moot).

// ---------------------------------------------------------------------------
// Kernel 1: global min/max over the gathered dist_t[h,w] values.
__global__ __launch_bounds__(256) void minmax_kernel(
    const float* __restrict__ dist,
    const int*   __restrict__ index_t,
    const int*   __restrict__ index_h,
    unsigned*    __restrict__ ws,
    int total4)  // total4 = H * WCOLS / 4
{
    float vmin = __int_as_float(0x7f800000);  // +inf
    float vmax = 0.0f;
    const int stride = gridDim.x * blockDim.x;
    for (int i4 = blockIdx.x * blockDim.x + threadIdx.x; i4 < total4; i4 += stride) {
        const int4 it = reinterpret_cast<const int4*>(index_t)[i4];
        const int  h  = i4 >> 3;              // (i4*4) >> 5
        const int  row = index_h[h] * DCOLS;  // 8 lanes share h -> broadcast
        float v0 = 0.0f, v1 = 0.0f, v2 = 0.0f, v3 = 0.0f;
        if (it.x < DCOLS) v0 = dist[row + it.x];
        if (it.y < DCOLS) v1 = dist[row + it.y];
        if (it.z < DCOLS) v2 = dist[row + it.z];
        if (it.w < DCOLS) v3 = dist[row + it.w];
        vmin = fminf(fminf(fminf(vmin, v0), fminf(v1, v2)), v3);
        vmax = fmaxf(fmaxf(fmaxf(vmax, v0), fmaxf(v1, v2)), v3);
    }
    #pragma unroll
    for (int off = 32; off > 0; off >>= 1) {
        vmin = fminf(vmin, __shfl_down(vmin, off, 64));
        vmax = fmaxf(vmax, __shfl_down(vmax, off, 64));
    }
    __shared__ float smin[4], smax[4];
    const int lane = threadIdx.x & 63;
    const int wave = threadIdx.x >> 6;
    if (lane == 0) { smin[wave] = vmin; smax[wave] = vmax; }
    __syncthreads();
    if (threadIdx.x == 0) {
        float m = smin[0], M = smax[0];
        #pragma unroll
        for (int k = 1; k < 4; ++k) { m = fminf(m, smin[k]); M = fmaxf(M, smax[k]); }
        atomicMin(ws,             __float_as_uint(-m));
        atomicMax((int*)(ws + 1), __float_as_int(M));
    }
}

// ---------------------------------------------------------------------------
// Kernel 2: R4's proven fill — 8 rows per 256-thread block, all threads
// gather, 6 contiguous float4 stores per thread — with PLAIN cached stores.
__global__ __launch_bounds__(256) void fill_kernel(
    const float* __restrict__ dist,
    const float* __restrict__ angle,
    const int*   __restrict__ idx_t,
    const int*   __restrict__ index_t,
    const int*   __restrict__ index_h,
    const unsigned* __restrict__ ws,
    float*       __restrict__ out,
    int H)
{
    const int h0  = blockIdx.x * ROWS_PER_BLOCK;
    const int tid = threadIdx.x;

    __shared__ int   s_idx[ROWS_PER_BLOCK][WCOLS];
    __shared__ float s_dist[ROWS_PER_BLOCK][WCOLS];
    __shared__ float s_angle[ROWS_PER_BLOCK][WCOLS];

    {
        const float dmin = -__uint_as_float(ws[0]);
        const float dmax =  __uint_as_float(ws[1]);
        const float inv  = 1.0f / (dmax - dmin);
        const int r = tid >> 5;
        const int c = tid & 31;
        const int h = h0 + r;
        if (h < H) {
            const int it = index_t[h * WCOLS + c];
            s_idx[r][c] = idx_t[h * WCOLS + c];
            float dv = 0.0f, av = 0.0f;
            if (it < DCOLS) {
                const int base = index_h[h] * DCOLS;
                dv = dist[base + it];
                av = angle[base + it];
            }
            s_dist[r][c]  = (dv - dmin) * inv;
            s_angle[r][c] = av;
        }
    }
    __syncthreads();

    const bool full = (h0 + ROWS_PER_BLOCK) <= H;
    #pragma unroll
    for (int m = 0; m < 6; ++m) {
        const int t    = m * 256 + tid;       // 0..1535 across the block
        const int row  = t / 192;             // const-div -> mul/shift
        const int col4 = t - row * 192;
        const int j0   = col4 * 4;
        float4 v4;
        float* vp = &v4.x;
        #pragma unroll
        for (int k = 0; k < 4; ++k) {
            const int j = j0 + k;
            float v;
            if (j < ONEHOT_COLS) {
                const int w = j / NUM_CLASSES;
                const int c = j - w * NUM_CLASSES;
                v = (s_idx[row][w] == c) ? 1.0f : 0.0f;
            } else if (j < ONEHOT_COLS + WCOLS) {
                v = s_dist[row][j - ONEHOT_COLS];
            } else {
                v = s_angle[row][j - (ONEHOT_COLS + WCOLS)];
            }
            vp[k] = v;
        }
        if (full) {
            float4* o = reinterpret_cast<float4*>(out + (size_t)h0 * OUT_COLS);
            o[t] = v4;
        } else if (h0 + row < H) {
            float4* o = reinterpret_cast<float4*>(
                out + (size_t)(h0 + row) * OUT_COLS);
            o[col4] = v4;
        }
    }
}

// ---------------------------------------------------------------------------
extern "C" void kernel_launch(void* const* d_in, const int* in_sizes, int n_in,
                              void* d_out, int out_size, void* d_ws, size_t ws_size,
                              hipStream_t stream) {
    const float* dist    = (const float*)d_in[0];
    const float* angle   = (const float*)d_in[1];
    const int*   idx_t   = (const int*)d_in[2];
    const int*   index_t = (const int*)d_in[3];
    const int*   index_h = (const int*)d_in[4];
    float*       out     = (float*)d_out;
    unsigned*    ws      = (unsigned*)d_ws;
    const int    H       = in_sizes[4];       // index_h has H elements

    // Seed min/max accumulators with 0xFFFFFFFF (see encoding above).
    (void)hipMemsetAsync(ws, 0xFF, 8, stream);

    const int total4 = (H * WCOLS) / 4;
    hipLaunchKernelGGL(minmax_kernel, dim3(2048), dim3(256), 0, stream,
                       dist, index_t, index_h, ws, total4);

    const int fill_blocks = (H + ROWS_PER_BLOCK - 1) / ROWS_PER_BLOCK;
    hipLaunchKernelGGL(fill_kernel, dim3(fill_blocks), dim3(256), 0, stream,
                       dist, angle, idx_t, index_t, index_h, ws, out, H);
}